// Round 5
// baseline (479.701 us; speedup 1.0000x reference)
//
#include <hip/hip_runtime.h>
#include <hip/hip_bf16.h>
#include <stdint.h>

// ---- problem constants (fixed shapes) ----
#define BTOT   256      // B*T frames
#define LX     197      // tokens incl CLS
#define CDIM   768
#define CADIM  384
#define TFR    8
#define LM1    196      // L-1
#define MTOT   50176    // BTOT*LM1

typedef unsigned short u16;
typedef short          bf16x8 __attribute__((ext_vector_type(8)));
typedef unsigned short u16x4  __attribute__((ext_vector_type(4)));
typedef unsigned short u16x8  __attribute__((ext_vector_type(8)));
typedef float          f32x4  __attribute__((ext_vector_type(4)));

typedef const __attribute__((address_space(1))) void gvoid_t;
typedef __attribute__((address_space(3))) void       svoid_t;

static __device__ __forceinline__ u16 f2bf(float f) {
  union { float f; uint32_t u; } v; v.f = f;
  uint32_t u = v.u;
  return (u16)((u + 0x7FFFu + ((u >> 16) & 1u)) >> 16);  // RNE
}
static __device__ __forceinline__ float bf2f(u16 h) {
  union { uint32_t u; float f; } v; v.u = ((uint32_t)h) << 16;
  return v.f;
}
// RNE f32->bf16 via intrinsic: compiler emits v_cvt_pk_bf16_f32 for pairs
// (m240: scalar casts codegen well; do NOT hand-write the asm).
static __device__ __forceinline__ u16 f2bf_hw(float f) {
  union { __hip_bfloat16 b; u16 u; } v;
  v.b = __float2bfloat16(f);
  return v.u;
}

// ------- prep: weights bf16 + conv_w transpose + CLS-row copy -------
__global__ void prep_small(const float4* __restrict__ x4, float4* __restrict__ out4,
                           const float* __restrict__ W1, const float* __restrict__ W2,
                           const float* __restrict__ cw, u16* __restrict__ w1b,
                           u16* __restrict__ w2b, float* __restrict__ cwT) {
  int i = blockIdx.x * blockDim.x + threadIdx.x;
  if (i < CADIM * CDIM) { w1b[i] = f2bf(W1[i]); w2b[i] = f2bf(W2[i]); }
  if (i < CADIM * 27) {
    int a = i / 27; int tap = i - a * 27;
    cwT[tap * CADIM + a] = cw[i];        // [27][384] channel-contiguous
  }
  if (i < BTOT * 192) {                  // CLS rows: 256 frames x 192 float4
    int f = i / 192, v = i - f * 192;
    size_t off = (size_t)f * (LX * CDIM / 4) + v;
    out4[off] = x4[off];
  }
}

// ======================================================================
// GEMM cores: 128x128 tile, BK=32.
// LDS layout per buffer: 64 "super-rows" of 128B, super-row R = rows
// {2R, 2R+1} (32 bf16 each). Unswizzled slot u (0..7): u<4 -> row 2R
// chunk u; u>=4 -> row 2R+1 chunk u-4. Physical slot = u ^ (R&7).
// ds_read_b128 frag reads land 2 lanes/bank (free, m136).
//
// fc1 (this round): A reg-staged from fp32 x with 2-DEEP register
// prefetch + raw s_barrier + counted vmcnt(4) -- A loads for tile t+2
// stay in flight ACROSS the barrier (full-iteration latency cover).
// Order-safety of the count: B gload_lds issued first each iter, pinned
// by one sched_barrier(0); vmcnt(4) then retires exactly the 2 B loads.
// fc2: R1-exact structure (best measured, 94.8 us).
// LDS = 2buf*(8K+8K) = 32 KB -> 5 blocks/CU LDS cap.
// ======================================================================

#define GEMM_STAGE2(bufidx, k0)                                            \
  {                                                                        \
    _Pragma("unroll")                                                      \
    for (int s = 0; s < 2; ++s) {                                          \
      __builtin_amdgcn_global_load_lds((gvoid_t*)(A + aoff[s] + (k0)),     \
          (svoid_t*)(As + (bufidx) * 4096 + ldst[s]), 16, 0, 0);           \
      __builtin_amdgcn_global_load_lds((gvoid_t*)(Bw + boff[s] + (k0)),    \
          (svoid_t*)(Bs + (bufidx) * 4096 + ldst[s]), 16, 0, 0);           \
    }                                                                      \
  }

#define GEMM_STAGE_B(bufidx, k0)                                           \
  {                                                                        \
    _Pragma("unroll")                                                      \
    for (int s = 0; s < 2; ++s) {                                          \
      __builtin_amdgcn_global_load_lds((gvoid_t*)(Bw + boff[s] + (k0)),    \
          (svoid_t*)(Bs + (bufidx) * 4096 + ldst[s]), 16, 0, 0);           \
    }                                                                      \
  }

#define GEMM_COMPUTE(bufidx)                                               \
  {                                                                        \
    const u16* Ab = As + (bufidx) * 4096;                                  \
    const u16* Bb = Bs + (bufidx) * 4096;                                  \
    bf16x8 af[4], bfr[4];                                                  \
    _Pragma("unroll")                                                      \
    for (int i = 0; i < 4; i++) af[i] = *(const bf16x8*)&Ab[abase + i * 512]; \
    _Pragma("unroll")                                                      \
    for (int j = 0; j < 4; j++) bfr[j] = *(const bf16x8*)&Bb[bbase + j * 512]; \
    _Pragma("unroll")                                                      \
    for (int i = 0; i < 4; i++)                                            \
      _Pragma("unroll")                                                    \
      for (int j = 0; j < 4; j++)                                          \
        acc[i][j] = __builtin_amdgcn_mfma_f32_16x16x32_bf16(af[i], bfr[j], acc[i][j], 0, 0, 0); \
  }

// convert A regs (float4 x4) -> bf16 (HW cvt_pk) and store to swizzled LDS
#define WRITE_A_REG(bufidx, R)                                             \
  {                                                                        \
    _Pragma("unroll")                                                      \
    for (int s = 0; s < 4; ++s) {                                          \
      u16x4 o;                                                             \
      o[0] = f2bf_hw(R[s].x); o[1] = f2bf_hw(R[s].y);                      \
      o[2] = f2bf_hw(R[s].z); o[3] = f2bf_hw(R[s].w);                      \
      *(u16x4*)&As[(bufidx) * 4096 + awst[s]] = o;                         \
    }                                                                      \
  }

// fc1 steady-state K-step for tile T (buf P), consuming A regs CUR
// (loaded 1 iter ago, for tile T+1) and issuing NXT = A(T+2).
// End wait: vmcnt(4) retires this iter's 2 B gloads, leaves NXT flying.
#define FC1_STEP(T, P, CUR, NXT)                                           \
  {                                                                        \
    GEMM_STAGE_B((P) ^ 1, ((T) + 1) * 32);                                 \
    __builtin_amdgcn_sched_barrier(0);  /* pin B issue before NXT */       \
    WRITE_A_REG((P) ^ 1, CUR);                                             \
    _Pragma("unroll")                                                      \
    for (int s = 0; s < 4; ++s)                                            \
      NXT[s] = *(const float4*)(X + arow[s] + ((T) + 2) * 32);             \
    GEMM_COMPUTE(P);                                                       \
    asm volatile("s_waitcnt vmcnt(4) lgkmcnt(0)" ::: "memory");            \
    __builtin_amdgcn_s_barrier();                                          \
  }

// ---------------- fc1: h1[m, a] = x[m,:] . W1[a,:] + b1[a] ----------------
// A = x fp32 (CLS-skipped row remap), converted in-register.
__global__ __launch_bounds__(256) void fc1_gemm(
    const float* __restrict__ X,  // x fp32 [BTOT][LX][CDIM]
    const u16* __restrict__ Bw,   // w1b [384][768] bf16 (N x K row-major)
    const float* __restrict__ bias,
    u16* __restrict__ Hout)       // [50176][384] bf16
{
  __shared__ __align__(16) u16 As[2 * 128 * 32];
  __shared__ __align__(16) u16 Bs[2 * 128 * 32];
  const int tid  = threadIdx.x;
  const int lane = tid & 63;
  const int wave = tid >> 6;
  const int m0 = blockIdx.x * 128;
  const int n0 = blockIdx.y * 128;
  const int lm = lane & 15;
  const int lk = lane >> 4;
  const int wm = (wave & 1) * 64;
  const int wn = (wave >> 1) * 64;

  // ---- B staging (gload_lds, linear dst): wave covers rows wave*32+s*16+rr
  const int u   = (lane & 7) ^ (lane >> 3);     // swizzled chunk fetch
  const int rr  = 2 * (lane >> 3) + (u >> 2);
  const int cko = (u & 3) * 8;
  size_t boff[2];
  int ldst[2];
#pragma unroll
  for (int s = 0; s < 2; ++s) {
    int row = wave * 32 + s * 16 + rr;
    boff[s] = (size_t)(n0 + row) * CDIM + cko;
    ldst[s] = (wave * 16 + s * 8) * 64;
  }

  // ---- A reg-staging: thread t covers rows g+32s (g=t>>3), float4 q=t&7
  const int g = tid >> 3;
  const int q = tid & 7;
  size_t arow[4];
  int awst[4];
#pragma unroll
  for (int s = 0; s < 4; ++s) {
    int row = g + 32 * s;
    int tok = m0 + row;
    int bt = tok / LM1;
    int l  = tok - bt * LM1;
    arow[s] = (size_t)(bt * LX + 1 + l) * CDIM + q * 4;   // fp32, skip CLS
    int R    = row >> 1;
    int uu   = (row & 1) * 4 + (q >> 1);
    int slot = uu ^ (R & 7);
    awst[s]  = R * 64 + slot * 8 + (q & 1) * 4;           // u16 elems
  }

  // fragment read addressing (swizzled): slot' = ((lm&1)*4 | lk) ^ (lm>>1)
  const int lmh   = lm >> 1;
  const int slotp = (((lm & 1) << 2) | lk) ^ lmh;
  const int abase = ((wm >> 1) + lmh) * 64 + slotp * 8;
  const int bbase = ((wn >> 1) + lmh) * 64 + slotp * 8;

  f32x4 acc[4][4];
#pragma unroll
  for (int i = 0; i < 4; i++)
#pragma unroll
    for (int j = 0; j < 4; j++) acc[i][j] = (f32x4)0.0f;

  float4 aregA[4], aregB[4];

  // ---- prologue: tile0 into buf0; A(1) left in flight across barrier ----
#pragma unroll
  for (int s = 0; s < 4; ++s) aregA[s] = *(const float4*)(X + arow[s]);  // A(0)
  GEMM_STAGE_B(0, 0);
  __builtin_amdgcn_sched_barrier(0);
  WRITE_A_REG(0, aregA);                 // compiler waits A(0) only
#pragma unroll
  for (int s = 0; s < 4; ++s) aregA[s] = *(const float4*)(X + arow[s] + 32); // A(1)
  asm volatile("s_waitcnt vmcnt(4) lgkmcnt(0)" ::: "memory");  // retire B(0)
  __builtin_amdgcn_s_barrier();

  // K = 768 -> 24 tiles; steady state t=0..21 (pair-unrolled for static regs)
  for (int t = 0; t < 22; t += 2) {
    FC1_STEP(t,     0, aregA, aregB);
    FC1_STEP(t + 1, 1, aregB, aregA);
  }
  // tail t=22: stage tile23 (B + A from aregA), no further loads
  GEMM_STAGE_B(1, 23 * 32);
  WRITE_A_REG(1, aregA);
  GEMM_COMPUTE(0);
  asm volatile("s_waitcnt vmcnt(0) lgkmcnt(0)" ::: "memory");
  __builtin_amdgcn_s_barrier();
  GEMM_COMPUTE(1);                        // tile23

#pragma unroll
  for (int i = 0; i < 4; i++) {
    int rbase = m0 + wm + i * 16 + lk * 4;
#pragma unroll
    for (int j = 0; j < 4; j++) {
      int col = n0 + wn + j * 16 + lm;
      float bv = bias[col];
#pragma unroll
      for (int r = 0; r < 4; r++)
        Hout[(rbase + r) * CADIM + col] = f2bf(acc[i][j][r] + bv);
    }
  }
}

// ---------------- depthwise 3x3x3 conv: 2x2 outputs/thread ----------------
__global__ __launch_bounds__(256) void dwconv(
    const u16* __restrict__ h1, const float* __restrict__ cwT,
    const float* __restrict__ cb, u16* __restrict__ h2)
{
  int idx = blockIdx.x * blockDim.x + threadIdx.x;   // < 256*49*48
  int cg = idx % 48;
  int rest = idx / 48;                 // frame*49 + hp*7 + wp
  int wp = rest % 7; rest /= 7;
  int hp = rest % 7; rest /= 7;        // rest = frame = b*8+t
  int t = rest & 7;
  int frame = rest;
  int a0 = cg * 8;
  int h0 = hp * 2, w0 = wp * 2;

  float acc[2][2][8];
#pragma unroll
  for (int c = 0; c < 8; ++c) {
    float bv = cb[a0 + c];
    acc[0][0][c] = bv; acc[0][1][c] = bv; acc[1][0][c] = bv; acc[1][1][c] = bv;
  }

#pragma unroll
  for (int dt = -1; dt <= 1; ++dt) {
    int tt = t + dt;
    if (tt < 0 || tt >= TFR) continue;
    // plane weights (9 taps x 8 ch) in registers, reused by all 4 outputs
    float wreg[9][8];
#pragma unroll
    for (int j = 0; j < 9; ++j) {
      const float* wp8 = cwT + ((dt + 1) * 9 + j) * CADIM + a0;
#pragma unroll
      for (int c = 0; c < 8; ++c) wreg[j][c] = wp8[c];
    }
    const u16* fbase = h1 + (size_t)(frame + dt) * LM1 * CADIM + a0;
#pragma unroll
    for (int ih = 0; ih < 4; ++ih) {
      int hh = h0 - 1 + ih;
      if (hh < 0 || hh >= 14) continue;
#pragma unroll
      for (int iw = 0; iw < 4; ++iw) {
        int ww = w0 - 1 + iw;
        if (ww < 0 || ww >= 14) continue;
        bf16x8 v = *(const bf16x8*)(fbase + (hh * 14 + ww) * CADIM);
        float vf[8];
#pragma unroll
        for (int c = 0; c < 8; ++c) vf[c] = bf2f((u16)v[c]);
#pragma unroll
        for (int oh = 0; oh < 2; ++oh) {
          if (ih - 1 - oh < -1 || ih - 1 - oh > 1) continue;   // compile-time
#pragma unroll
          for (int ow = 0; ow < 2; ++ow) {
            if (iw - 1 - ow < -1 || iw - 1 - ow > 1) continue; // compile-time
            int j = (ih - oh) * 3 + (iw - ow);                 // (dh+1)*3 + (dw+1)
#pragma unroll
            for (int c = 0; c < 8; ++c)
              acc[oh][ow][c] += vf[c] * wreg[j][c];
          }
        }
      }
    }
  }
  const size_t obase = (size_t)frame * LM1 * CADIM + a0;
#pragma unroll
  for (int oh = 0; oh < 2; ++oh)
#pragma unroll
    for (int ow = 0; ow < 2; ++ow) {
      u16x8 o;
#pragma unroll
      for (int c = 0; c < 8; ++c) o[c] = f2bf(acc[oh][ow][c]);
      *(u16x8*)(h2 + obase + ((size_t)(h0 + oh) * 14 + w0 + ow) * CADIM) = o;
    }
}

// ---------------- fc2 + residual: out = x + h2 . W2^T + b2 ----------------
__global__ __launch_bounds__(256) void fc2_gemm(
    const u16* __restrict__ A,    // h2 [50176][384] bf16
    const u16* __restrict__ Bw,   // w2b [768][384] bf16 (N x K row-major)
    const float* __restrict__ bias,
    const float* __restrict__ x,
    float* __restrict__ out)
{
  __shared__ __align__(16) u16 As[2 * 128 * 32];
  __shared__ __align__(16) u16 Bs[2 * 128 * 32];
  const int tid  = threadIdx.x;
  const int lane = tid & 63;
  const int wave = tid >> 6;
  const int m0 = blockIdx.x * 128;
  const int n0 = blockIdx.y * 128;
  const int lm = lane & 15;
  const int lk = lane >> 4;
  const int wm = (wave & 1) * 64;
  const int wn = (wave >> 1) * 64;

  const int u   = (lane & 7) ^ (lane >> 3);
  const int rr  = 2 * (lane >> 3) + (u >> 2);
  const int cko = (u & 3) * 8;
  size_t aoff[2], boff[2];
  int ldst[2];
#pragma unroll
  for (int s = 0; s < 2; ++s) {
    int row = wave * 32 + s * 16 + rr;
    aoff[s] = (size_t)(m0 + row) * CADIM + cko;
    boff[s] = (size_t)(n0 + row) * CADIM + cko;
    ldst[s] = (wave * 16 + s * 8) * 64;
  }

  const int lmh   = lm >> 1;
  const int slotp = (((lm & 1) << 2) | lk) ^ lmh;
  const int abase = ((wm >> 1) + lmh) * 64 + slotp * 8;
  const int bbase = ((wn >> 1) + lmh) * 64 + slotp * 8;

  f32x4 acc[4][4];
#pragma unroll
  for (int i = 0; i < 4; i++)
#pragma unroll
    for (int j = 0; j < 4; j++) acc[i][j] = (f32x4)0.0f;

  // K = 384 -> 12 steps of 32, double-buffered (R1-exact)
  GEMM_STAGE2(0, 0);
  __syncthreads();
  int cur = 0;
  for (int kt = 0; kt < 11; ++kt) {
    GEMM_STAGE2(cur ^ 1, (kt + 1) * 32);
    GEMM_COMPUTE(cur);
    __syncthreads();
    cur ^= 1;
  }
  GEMM_COMPUTE(cur);

  // epilogue (R1-exact, best measured): residual add + bias, fp32 out.
  // Batched per quadrant: issue all 16 x-loads, then all 16 add+stores.
  float bv[4];
#pragma unroll
  for (int j = 0; j < 4; j++) bv[j] = bias[n0 + wn + j * 16 + lm];
#pragma unroll
  for (int i = 0; i < 4; i++) {
    int rbase = m0 + wm + i * 16 + lk * 4;
    size_t orow[4];
#pragma unroll
    for (int r = 0; r < 4; r++) {
      int tok = rbase + r;
      int bt = tok / LM1;
      int l  = tok - bt * LM1;
      orow[r] = (size_t)(bt * LX + 1 + l) * CDIM + (n0 + wn + lm);
    }
    float xv[4][4];
#pragma unroll
    for (int r = 0; r < 4; r++)
#pragma unroll
      for (int j = 0; j < 4; j++)
        xv[r][j] = x[orow[r] + j * 16];
#pragma unroll
    for (int r = 0; r < 4; r++)
#pragma unroll
      for (int j = 0; j < 4; j++)
        out[orow[r] + j * 16] = xv[r][j] + acc[i][j][r] + bv[j];
  }
}

// ---------------- launch ----------------
extern "C" void kernel_launch(void* const* d_in, const int* in_sizes, int n_in,
                              void* d_out, int out_size, void* d_ws, size_t ws_size,
                              hipStream_t stream) {
  const float* x  = (const float*)d_in[0];
  const float* W1 = (const float*)d_in[1];
  const float* b1 = (const float*)d_in[2];
  const float* cw = (const float*)d_in[3];
  const float* cb = (const float*)d_in[4];
  const float* W2 = (const float*)d_in[5];
  const float* b2 = (const float*)d_in[6];
  float* out = (float*)d_out;

  // workspace: 78.3 MB total
  char* ws = (char*)d_ws;
  u16*   w1b = (u16*)(ws + 0);              //    589,824 B
  u16*   w2b = (u16*)(ws + 589824);         //    589,824 B
  float* cwT = (float*)(ws + 1179648);      //     41,472 B
  u16*   h1  = (u16*)(ws + 1245184);        // 38,535,168 B
  u16*   h2  = (u16*)(ws + 39780352);       // 38,535,168 B  (end 78,315,520)

  prep_small<<<1152, 256, 0, stream>>>((const float4*)x, (float4*)out,
                                       W1, W2, cw, w1b, w2b, cwT);
  fc1_gemm<<<dim3(MTOT / 128, CADIM / 128), 256, 0, stream>>>(x, w1b, b1, h1);
  dwconv  <<<(BTOT * 49 * 48) / 256, 256, 0, stream>>>(h1, cwT, cb, h2);
  fc2_gemm<<<dim3(MTOT / 128, CDIM / 128), 256, 0, stream>>>(h2, w2b, b2, x, out);
}

// Round 6
// 445.997 us; speedup vs baseline: 1.0756x; 1.0756x over previous
//
#include <hip/hip_runtime.h>
#include <hip/hip_bf16.h>
#include <stdint.h>

// ---- problem constants (fixed shapes) ----
#define BTOT   256      // B*T frames
#define LX     197      // tokens incl CLS
#define CDIM   768
#define CADIM  384
#define TFR    8
#define LM1    196      // L-1
#define MTOT   50176    // BTOT*LM1

typedef unsigned short u16;
typedef short          bf16x8 __attribute__((ext_vector_type(8)));
typedef unsigned short u16x4  __attribute__((ext_vector_type(4)));
typedef unsigned short u16x8  __attribute__((ext_vector_type(8)));
typedef float          f32x4  __attribute__((ext_vector_type(4)));

typedef const __attribute__((address_space(1))) void gvoid_t;
typedef __attribute__((address_space(3))) void       svoid_t;

static __device__ __forceinline__ u16 f2bf(float f) {
  union { float f; uint32_t u; } v; v.f = f;
  uint32_t u = v.u;
  return (u16)((u + 0x7FFFu + ((u >> 16) & 1u)) >> 16);  // RNE
}
static __device__ __forceinline__ float bf2f(u16 h) {
  union { uint32_t u; float f; } v; v.u = ((uint32_t)h) << 16;
  return v.f;
}
// RNE f32->bf16 via intrinsic (compiler emits packed cvt where possible)
static __device__ __forceinline__ u16 f2bf_hw(float f) {
  union { __hip_bfloat16 b; u16 u; } v;
  v.b = __float2bfloat16(f);
  return v.u;
}

// ------- prep: weights bf16 + conv_w transpose + CLS-row copy -------
__global__ void prep_small(const float4* __restrict__ x4, float4* __restrict__ out4,
                           const float* __restrict__ W1, const float* __restrict__ W2,
                           const float* __restrict__ cw, u16* __restrict__ w1b,
                           u16* __restrict__ w2b, float* __restrict__ cwT) {
  int i = blockIdx.x * blockDim.x + threadIdx.x;
  if (i < CADIM * CDIM) { w1b[i] = f2bf(W1[i]); w2b[i] = f2bf(W2[i]); }
  if (i < CADIM * 27) {
    int a = i / 27; int tap = i - a * 27;
    cwT[tap * CADIM + a] = cw[i];        // [27][384] channel-contiguous
  }
  if (i < BTOT * 192) {                  // CLS rows: 256 frames x 192 float4
    int f = i / 192, v = i - f * 192;
    size_t off = (size_t)f * (LX * CDIM / 4) + v;
    out4[off] = x4[off];
  }
}

// ======================================================================
// LDS layout (both GEMMs, per buffer, per operand): super-row R (128 B)
// holds rows {2R, 2R+1} (32 bf16 each). Unswizzled slot u (0..7): u<4 ->
// row 2R chunk u; u>=4 -> row 2R+1 chunk u-4. Physical slot = u ^ (R&7).
// ds_read_b128 frag reads land 2 lanes/bank (free, m136); gload_lds
// destinations stay linear.
//
// fc1 (this round): BM=128 x BN=384 (FULL N) -> x staged exactly ONCE
// (R4 grid staged it 3x; session data shows per-K-step cost scales with
// staged bytes, so -45% staged volume). 768 thr / 12 waves (2M x 6N,
// per-wave 64x64 = the proven 4x4-fragment code). Wave-specialized
// staging: waves 0-3 reg-stage A from fp32 x (R4 path), waves 4-11
// stage B via global_load_lds. 2-phase dbuf, __syncthreads (the only
// structure that has never regressed here). LDS 16+48 = 64 KB -> 2
// blocks/CU (24 waves/CU).
// fc2: R1-exact structure (best measured, 94.8 us).
// ======================================================================

#define GEMM_STAGE2(bufidx, k0)                                            \
  {                                                                        \
    _Pragma("unroll")                                                      \
    for (int s = 0; s < 2; ++s) {                                          \
      __builtin_amdgcn_global_load_lds((gvoid_t*)(A + aoff[s] + (k0)),     \
          (svoid_t*)(As + (bufidx) * 4096 + ldst[s]), 16, 0, 0);           \
      __builtin_amdgcn_global_load_lds((gvoid_t*)(Bw + boff[s] + (k0)),    \
          (svoid_t*)(Bs + (bufidx) * 4096 + ldst[s]), 16, 0, 0);           \
    }                                                                      \
  }

#define GEMM_COMPUTE(bufidx)                                               \
  {                                                                        \
    const u16* Ab = As + (bufidx) * 4096;                                  \
    const u16* Bb = Bs + (bufidx) * 4096;                                  \
    bf16x8 af[4], bfr[4];                                                  \
    _Pragma("unroll")                                                      \
    for (int i = 0; i < 4; i++) af[i] = *(const bf16x8*)&Ab[abase + i * 512]; \
    _Pragma("unroll")                                                      \
    for (int j = 0; j < 4; j++) bfr[j] = *(const bf16x8*)&Bb[bbase + j * 512]; \
    _Pragma("unroll")                                                      \
    for (int i = 0; i < 4; i++)                                            \
      _Pragma("unroll")                                                    \
      for (int j = 0; j < 4; j++)                                          \
        acc[i][j] = __builtin_amdgcn_mfma_f32_16x16x32_bf16(af[i], bfr[j], acc[i][j], 0, 0, 0); \
  }

// ---------------- fc1: h1[m, a] = x[m,:] . W1[a,:] + b1[a] ----------------
// BM=128, BN=384 (full N), 768 threads. A = x fp32 (CLS-skip), in-register
// cvt by waves 0-3; B = w1b staged by waves 4-11 via global_load_lds.
__global__ __launch_bounds__(768, 2) void fc1_gemm(
    const float* __restrict__ X,  // x fp32 [BTOT][LX][CDIM]
    const u16* __restrict__ Bw,   // w1b [384][768] bf16 (N x K row-major)
    const float* __restrict__ bias,
    u16* __restrict__ Hout)       // [50176][384] bf16
{
  __shared__ __align__(16) u16 As[2 * 128 * 32];   // 16 KB
  __shared__ __align__(16) u16 Bs[2 * 384 * 32];   // 48 KB
  const int tid  = threadIdx.x;
  const int lane = tid & 63;
  const int wave = tid >> 6;           // 0..11
  const int m0 = blockIdx.x * 128;
  const int lm = lane & 15;
  const int lk = lane >> 4;
  const int wr = wave / 6;             // 0..1  (M half)
  const int wc = wave - wr * 6;        // 0..5  (N sixth)
  const int wm = wr * 64;
  const int wn = wc * 64;
  const bool is_a = (wave < 4);

  // ---- A reg-staging (waves 0-3): thread t: rows g+32s (g=t>>3), float4 q
  const int g = tid >> 3;              // 0..31 when is_a
  const int q = tid & 7;
  size_t arow[4];
  int awst[4];
  if (is_a) {
#pragma unroll
    for (int s = 0; s < 4; ++s) {
      int row = g + 32 * s;
      int tok = m0 + row;
      int bt = tok / LM1;
      int l  = tok - bt * LM1;
      arow[s] = (size_t)(bt * LX + 1 + l) * CDIM + q * 4;   // fp32, skip CLS
      int R    = row >> 1;
      int uu   = (row & 1) * 4 + (q >> 1);
      int slot = uu ^ (R & 7);
      awst[s]  = R * 64 + slot * 8 + (q & 1) * 4;           // u16 elems
    }
  }

  // ---- B staging (waves 4-11): 8 waves x 3 instrs cover 384 rows.
  // Instr (wb,s) covers rows wb*48+s*16 .. +15 (8 super-rows, base %8==0
  // so the R1 swizzle-fetch formula carries over unchanged).
  const int wb  = wave - 4;            // 0..7 when !is_a
  const int u   = (lane & 7) ^ (lane >> 3);
  const int rr  = 2 * (lane >> 3) + (u >> 2);
  const int cko = (u & 3) * 8;
  size_t boff[3];
  int ldst[3];
  if (!is_a) {
#pragma unroll
    for (int s = 0; s < 3; ++s) {
      int row = wb * 48 + s * 16 + rr;
      boff[s] = (size_t)row * CDIM + cko;
      ldst[s] = (wb * 24 + s * 8) * 64;                     // u16 elems
    }
  }

  // fragment read addressing (swizzled)
  const int lmh   = lm >> 1;
  const int slotp = (((lm & 1) << 2) | lk) ^ lmh;
  const int abase = ((wm >> 1) + lmh) * 64 + slotp * 8;
  const int bbase = ((wn >> 1) + lmh) * 64 + slotp * 8;

  f32x4 acc[4][4];
#pragma unroll
  for (int i = 0; i < 4; i++)
#pragma unroll
    for (int j = 0; j < 4; j++) acc[i][j] = (f32x4)0.0f;

  float4 areg[4];

  // ---- prologue: tile 0 ----
  if (is_a) {
#pragma unroll
    for (int s = 0; s < 4; ++s) areg[s] = *(const float4*)(X + arow[s]);
#pragma unroll
    for (int s = 0; s < 4; ++s) {
      u16x4 o;
      o[0] = f2bf_hw(areg[s].x); o[1] = f2bf_hw(areg[s].y);
      o[2] = f2bf_hw(areg[s].z); o[3] = f2bf_hw(areg[s].w);
      *(u16x4*)&As[awst[s]] = o;
    }
  } else {
#pragma unroll
    for (int s = 0; s < 3; ++s)
      __builtin_amdgcn_global_load_lds((gvoid_t*)(Bw + boff[s]),
          (svoid_t*)(Bs + ldst[s]), 16, 0, 0);
  }
  __syncthreads();

  // ---- K = 768 -> 24 steps of 32, 2-phase double-buffered ----
  int cur = 0;
  for (int kt = 0; kt < 23; ++kt) {
    const int k1 = (kt + 1) * 32;
    const int nb = cur ^ 1;
    if (is_a) {
#pragma unroll
      for (int s = 0; s < 4; ++s) areg[s] = *(const float4*)(X + arow[s] + k1);
    } else {
#pragma unroll
      for (int s = 0; s < 3; ++s)
        __builtin_amdgcn_global_load_lds((gvoid_t*)(Bw + boff[s] + k1),
            (svoid_t*)(Bs + nb * 12288 + ldst[s]), 16, 0, 0);
    }
    {
      const u16* Ab = As + cur * 4096;
      const u16* Bb = Bs + cur * 12288;
      bf16x8 af[4], bfr[4];
#pragma unroll
      for (int i = 0; i < 4; i++) af[i] = *(const bf16x8*)&Ab[abase + i * 512];
#pragma unroll
      for (int j = 0; j < 4; j++) bfr[j] = *(const bf16x8*)&Bb[bbase + j * 512];
#pragma unroll
      for (int i = 0; i < 4; i++)
#pragma unroll
        for (int j = 0; j < 4; j++)
          acc[i][j] = __builtin_amdgcn_mfma_f32_16x16x32_bf16(af[i], bfr[j], acc[i][j], 0, 0, 0);
    }
    if (is_a) {
#pragma unroll
      for (int s = 0; s < 4; ++s) {
        u16x4 o;
        o[0] = f2bf_hw(areg[s].x); o[1] = f2bf_hw(areg[s].y);
        o[2] = f2bf_hw(areg[s].z); o[3] = f2bf_hw(areg[s].w);
        *(u16x4*)&As[nb * 4096 + awst[s]] = o;
      }
    }
    __syncthreads();
    cur ^= 1;
  }
  {
    const u16* Ab = As + cur * 4096;
    const u16* Bb = Bs + cur * 12288;
    bf16x8 af[4], bfr[4];
#pragma unroll
    for (int i = 0; i < 4; i++) af[i] = *(const bf16x8*)&Ab[abase + i * 512];
#pragma unroll
    for (int j = 0; j < 4; j++) bfr[j] = *(const bf16x8*)&Bb[bbase + j * 512];
#pragma unroll
    for (int i = 0; i < 4; i++)
#pragma unroll
      for (int j = 0; j < 4; j++)
        acc[i][j] = __builtin_amdgcn_mfma_f32_16x16x32_bf16(af[i], bfr[j], acc[i][j], 0, 0, 0);
  }

#pragma unroll
  for (int i = 0; i < 4; i++) {
    int rbase = m0 + wm + i * 16 + lk * 4;
#pragma unroll
    for (int j = 0; j < 4; j++) {
      int col = wn + j * 16 + lm;
      float bv = bias[col];
#pragma unroll
      for (int r = 0; r < 4; r++)
        Hout[(rbase + r) * CADIM + col] = f2bf(acc[i][j][r] + bv);
    }
  }
}

// ---------------- depthwise 3x3x3 conv: 2x2 outputs/thread ----------------
__global__ __launch_bounds__(256) void dwconv(
    const u16* __restrict__ h1, const float* __restrict__ cwT,
    const float* __restrict__ cb, u16* __restrict__ h2)
{
  int idx = blockIdx.x * blockDim.x + threadIdx.x;   // < 256*49*48
  int cg = idx % 48;
  int rest = idx / 48;                 // frame*49 + hp*7 + wp
  int wp = rest % 7; rest /= 7;
  int hp = rest % 7; rest /= 7;        // rest = frame = b*8+t
  int t = rest & 7;
  int frame = rest;
  int a0 = cg * 8;
  int h0 = hp * 2, w0 = wp * 2;

  float acc[2][2][8];
#pragma unroll
  for (int c = 0; c < 8; ++c) {
    float bv = cb[a0 + c];
    acc[0][0][c] = bv; acc[0][1][c] = bv; acc[1][0][c] = bv; acc[1][1][c] = bv;
  }

#pragma unroll
  for (int dt = -1; dt <= 1; ++dt) {
    int tt = t + dt;
    if (tt < 0 || tt >= TFR) continue;
    // plane weights (9 taps x 8 ch) in registers, reused by all 4 outputs
    float wreg[9][8];
#pragma unroll
    for (int j = 0; j < 9; ++j) {
      const float* wp8 = cwT + ((dt + 1) * 9 + j) * CADIM + a0;
#pragma unroll
      for (int c = 0; c < 8; ++c) wreg[j][c] = wp8[c];
    }
    const u16* fbase = h1 + (size_t)(frame + dt) * LM1 * CADIM + a0;
#pragma unroll
    for (int ih = 0; ih < 4; ++ih) {
      int hh = h0 - 1 + ih;
      if (hh < 0 || hh >= 14) continue;
#pragma unroll
      for (int iw = 0; iw < 4; ++iw) {
        int ww = w0 - 1 + iw;
        if (ww < 0 || ww >= 14) continue;
        bf16x8 v = *(const bf16x8*)(fbase + (hh * 14 + ww) * CADIM);
        float vf[8];
#pragma unroll
        for (int c = 0; c < 8; ++c) vf[c] = bf2f((u16)v[c]);
#pragma unroll
        for (int oh = 0; oh < 2; ++oh) {
          if (ih - 1 - oh < -1 || ih - 1 - oh > 1) continue;   // compile-time
#pragma unroll
          for (int ow = 0; ow < 2; ++ow) {
            if (iw - 1 - ow < -1 || iw - 1 - ow > 1) continue; // compile-time
            int j = (ih - oh) * 3 + (iw - ow);                 // (dh+1)*3 + (dw+1)
#pragma unroll
            for (int c = 0; c < 8; ++c)
              acc[oh][ow][c] += vf[c] * wreg[j][c];
          }
        }
      }
    }
  }
  const size_t obase = (size_t)frame * LM1 * CADIM + a0;
#pragma unroll
  for (int oh = 0; oh < 2; ++oh)
#pragma unroll
    for (int ow = 0; ow < 2; ++ow) {
      u16x8 o;
#pragma unroll
      for (int c = 0; c < 8; ++c) o[c] = f2bf(acc[oh][ow][c]);
      *(u16x8*)(h2 + obase + ((size_t)(h0 + oh) * 14 + w0 + ow) * CADIM) = o;
    }
}

// ---------------- fc2 + residual: out = x + h2 . W2^T + b2 ----------------
__global__ __launch_bounds__(256) void fc2_gemm(
    const u16* __restrict__ A,    // h2 [50176][384] bf16
    const u16* __restrict__ Bw,   // w2b [768][384] bf16 (N x K row-major)
    const float* __restrict__ bias,
    const float* __restrict__ x,
    float* __restrict__ out)
{
  __shared__ __align__(16) u16 As[2 * 128 * 32];
  __shared__ __align__(16) u16 Bs[2 * 128 * 32];
  const int tid  = threadIdx.x;
  const int lane = tid & 63;
  const int wave = tid >> 6;
  const int m0 = blockIdx.x * 128;
  const int n0 = blockIdx.y * 128;
  const int lm = lane & 15;
  const int lk = lane >> 4;
  const int wm = (wave & 1) * 64;
  const int wn = (wave >> 1) * 64;

  const int u   = (lane & 7) ^ (lane >> 3);
  const int rr  = 2 * (lane >> 3) + (u >> 2);
  const int cko = (u & 3) * 8;
  size_t aoff[2], boff[2];
  int ldst[2];
#pragma unroll
  for (int s = 0; s < 2; ++s) {
    int row = wave * 32 + s * 16 + rr;
    aoff[s] = (size_t)(m0 + row) * CADIM + cko;
    boff[s] = (size_t)(n0 + row) * CADIM + cko;
    ldst[s] = (wave * 16 + s * 8) * 64;
  }

  const int lmh   = lm >> 1;
  const int slotp = (((lm & 1) << 2) | lk) ^ lmh;
  const int abase = ((wm >> 1) + lmh) * 64 + slotp * 8;
  const int bbase = ((wn >> 1) + lmh) * 64 + slotp * 8;

  f32x4 acc[4][4];
#pragma unroll
  for (int i = 0; i < 4; i++)
#pragma unroll
    for (int j = 0; j < 4; j++) acc[i][j] = (f32x4)0.0f;

  // K = 384 -> 12 steps of 32, double-buffered (R1-exact)
  GEMM_STAGE2(0, 0);
  __syncthreads();
  int cur = 0;
  for (int kt = 0; kt < 11; ++kt) {
    GEMM_STAGE2(cur ^ 1, (kt + 1) * 32);
    GEMM_COMPUTE(cur);
    __syncthreads();
    cur ^= 1;
  }
  GEMM_COMPUTE(cur);

  // epilogue (R1-exact, best measured): residual add + bias, fp32 out.
  float bv[4];
#pragma unroll
  for (int j = 0; j < 4; j++) bv[j] = bias[n0 + wn + j * 16 + lm];
#pragma unroll
  for (int i = 0; i < 4; i++) {
    int rbase = m0 + wm + i * 16 + lk * 4;
    size_t orow[4];
#pragma unroll
    for (int r = 0; r < 4; r++) {
      int tok = rbase + r;
      int bt = tok / LM1;
      int l  = tok - bt * LM1;
      orow[r] = (size_t)(bt * LX + 1 + l) * CDIM + (n0 + wn + lm);
    }
    float xv[4][4];
#pragma unroll
    for (int r = 0; r < 4; r++)
#pragma unroll
      for (int j = 0; j < 4; j++)
        xv[r][j] = x[orow[r] + j * 16];
#pragma unroll
    for (int r = 0; r < 4; r++)
#pragma unroll
      for (int j = 0; j < 4; j++)
        out[orow[r] + j * 16] = xv[r][j] + acc[i][j][r] + bv[j];
  }
}

// ---------------- launch ----------------
extern "C" void kernel_launch(void* const* d_in, const int* in_sizes, int n_in,
                              void* d_out, int out_size, void* d_ws, size_t ws_size,
                              hipStream_t stream) {
  const float* x  = (const float*)d_in[0];
  const float* W1 = (const float*)d_in[1];
  const float* b1 = (const float*)d_in[2];
  const float* cw = (const float*)d_in[3];
  const float* cb = (const float*)d_in[4];
  const float* W2 = (const float*)d_in[5];
  const float* b2 = (const float*)d_in[6];
  float* out = (float*)d_out;

  // workspace: 78.3 MB total
  char* ws = (char*)d_ws;
  u16*   w1b = (u16*)(ws + 0);              //    589,824 B
  u16*   w2b = (u16*)(ws + 589824);         //    589,824 B
  float* cwT = (float*)(ws + 1179648);      //     41,472 B
  u16*   h1  = (u16*)(ws + 1245184);        // 38,535,168 B
  u16*   h2  = (u16*)(ws + 39780352);       // 38,535,168 B  (end 78,315,520)

  prep_small<<<1152, 256, 0, stream>>>((const float4*)x, (float4*)out,
                                       W1, W2, cw, w1b, w2b, cwT);
  fc1_gemm<<<MTOT / 128, 768, 0, stream>>>(x, w1b, b1, h1);
  dwconv  <<<(BTOT * 49 * 48) / 256, 256, 0, stream>>>(h1, cwT, cb, h2);
  fc2_gemm<<<dim3(MTOT / 128, CDIM / 128), 256, 0, stream>>>(h2, w2b, b2, x, out);
}